// Round 12
// baseline (632.584 us; speedup 1.0000x reference)
//
#include <hip/hip_runtime.h>
#include <math.h>

#define Bsz 1024
#define Npt 50
#define Hd 128
#define G4 512
#define Tt 50
#define NEGC 1000000000.0f
#define CTANH 10.0f

#define OFF_R 0
#define OFF_V 1024
#define OFF_LP 2048
#define OFF_A 2562048
#define OFF_C 2613248
#define OFF_P 2715648

// ws float offsets (all tables; no bulk state)
#define WS_TG 0        // 128 float4 {Mg0, Mg1, vg, cg}
#define WS_TP 512      // 128 float4 {Mp0, Mp1, vp, cp}
#define WS_TQ 1024     // 128 float4 {Pg0, Pg1, cg@Wqp+cp, 0}
#define WS_A0 1536     // 512: We0@Wi
#define WS_A1 2048     // 512: We1@Wi
#define WS_A2 2560     // 512: bemb@Wi + bl
#define WS_A3 3072     // 512: dec_init@Wi + bl   (step 0)
#define WS_CT 3584     // 128 float4 {T0, T1, Tc(+b1), W2}

__device__ __forceinline__ float fsig(float x) {
  return __builtin_amdgcn_rcpf(1.0f + __expf(-x));
}

// branchless tanh: abs err ~2e-7 (rcp ulp)
__device__ __forceinline__ float ftanh(float x) {
  float e = __expf(2.0f * x);
  return 1.0f - 2.0f * __builtin_amdgcn_rcpf(e + 1.0f);
}

// wave64 sum via DPP; result broadcast from lane 63
__device__ __forceinline__ float dpp_sum_bcast(float x) {
  int v;
  v = __builtin_amdgcn_update_dpp(0, __float_as_int(x), 0x111, 0xf, 0xf, true);
  x += __int_as_float(v);
  v = __builtin_amdgcn_update_dpp(0, __float_as_int(x), 0x112, 0xf, 0xf, true);
  x += __int_as_float(v);
  v = __builtin_amdgcn_update_dpp(0, __float_as_int(x), 0x114, 0xf, 0xf, true);
  x += __int_as_float(v);
  v = __builtin_amdgcn_update_dpp(0, __float_as_int(x), 0x118, 0xf, 0xf, true);
  x += __int_as_float(v);
  v = __builtin_amdgcn_update_dpp(0, __float_as_int(x), 0x142, 0xf, 0xf, true);
  x += __int_as_float(v);
  v = __builtin_amdgcn_update_dpp(0, __float_as_int(x), 0x143, 0xf, 0xf, true);
  x += __int_as_float(v);
  return __int_as_float(__builtin_amdgcn_readlane(__float_as_int(x), 63));
}

// wave64 max via DPP; REQUIRES x >= 0 (bound_ctrl zero-fill enters fmax)
__device__ __forceinline__ float dpp_max_bcast(float x) {
  int v;
  v = __builtin_amdgcn_update_dpp(0, __float_as_int(x), 0x111, 0xf, 0xf, true);
  x = fmaxf(x, __int_as_float(v));
  v = __builtin_amdgcn_update_dpp(0, __float_as_int(x), 0x112, 0xf, 0xf, true);
  x = fmaxf(x, __int_as_float(v));
  v = __builtin_amdgcn_update_dpp(0, __float_as_int(x), 0x114, 0xf, 0xf, true);
  x = fmaxf(x, __int_as_float(v));
  v = __builtin_amdgcn_update_dpp(0, __float_as_int(x), 0x118, 0xf, 0xf, true);
  x = fmaxf(x, __int_as_float(v));
  v = __builtin_amdgcn_update_dpp(0, __float_as_int(x), 0x142, 0xf, 0xf, true);
  x = fmaxf(x, __int_as_float(v));
  v = __builtin_amdgcn_update_dpp(0, __float_as_int(x), 0x143, 0xf, 0xf, true);
  x = fmaxf(x, __int_as_float(v));
  return __int_as_float(__builtin_amdgcn_readlane(__float_as_int(x), 63));
}

__device__ __forceinline__ float xsum(float x) {
  #pragma unroll
  for (int off = 32; off >= 1; off >>= 1) x += __shfl_xor(x, off, 64);
  return x;
}

// One block, 512 threads: all rank-2 tables + collapsed critic tables.
__global__ __launch_bounds__(512) void k_pre(const float* __restrict__ Wemb,
                                             const float* __restrict__ bemb,
                                             const float* __restrict__ dinit,
                                             const float* __restrict__ Wi,
                                             const float* __restrict__ bl,
                                             const float* __restrict__ Wqp,
                                             const float* __restrict__ Wrg,
                                             const float* __restrict__ Wrp,
                                             const float* __restrict__ vg,
                                             const float* __restrict__ vp,
                                             const float* __restrict__ Wrc,
                                             const float* __restrict__ W1,
                                             const float* __restrict__ b1,
                                             const float* __restrict__ W2,
                                             float* __restrict__ ws) {
  __shared__ float mg_s[2][128], mp_s[2][128], cg_s[128], cp_s[128];
  __shared__ float pg_s[2][128], pc_s[128];
  __shared__ float r0_s[128], r1_s[128], rc_s[128];
  int t = threadIdx.x;
  if (t < 256) {
    int j = t >> 7, hh = t & 127;
    float ag = 0.f, ap = 0.f;
    for (int k = 0; k < 128; ++k) {
      float we = Wemb[j * 128 + k];
      ag = fmaf(we, Wrg[k * 128 + hh], ag);
      ap = fmaf(we, Wrp[k * 128 + hh], ap);
    }
    mg_s[j][hh] = ag; mp_s[j][hh] = ap;
  } else if (t < 384) {
    int hh = t & 127;
    float cgv = 0.f, cpv = 0.f;
    for (int k = 0; k < 128; ++k) {
      float be = bemb[k];
      cgv = fmaf(be, Wrg[k * 128 + hh], cgv);
      cpv = fmaf(be, Wrp[k * 128 + hh], cpv);
    }
    cg_s[hh] = cgv; cp_s[hh] = cpv;
  } else {
    int hh = t & 127;
    float a0 = 0.f, a1 = 0.f, ac = 0.f;
    for (int k = 0; k < 128; ++k) {
      float wr = Wrc[k * 128 + hh];
      a0 = fmaf(Wemb[k], wr, a0);
      a1 = fmaf(Wemb[128 + k], wr, a1);
      ac = fmaf(bemb[k], wr, ac);
    }
    r0_s[hh] = a0; r1_s[hh] = a1; rc_s[hh] = ac;
  }
  __syncthreads();
  if (t < 256) {
    int j = t >> 7, hh = t & 127;
    float pg = 0.f;
    for (int k = 0; k < 128; ++k) pg = fmaf(mg_s[j][k], Wqp[k * 128 + hh], pg);
    pg_s[j][hh] = pg;
  } else if (t < 384) {
    int hh = t & 127;
    float pcv = 0.f;
    for (int k = 0; k < 128; ++k) pcv = fmaf(cg_s[k], Wqp[k * 128 + hh], pcv);
    pc_s[hh] = pcv + cp_s[hh];
  } else {
    int hh = t & 127;
    float t0 = 0.f, t1 = 0.f, tc = 0.f;
    for (int k = 0; k < 128; ++k) {
      float w1 = W1[k * 128 + hh];
      t0 = fmaf(r0_s[k], w1, t0);
      t1 = fmaf(r1_s[k], w1, t1);
      tc = fmaf(rc_s[k], w1, tc);
    }
    float4* w4 = (float4*)ws;
    w4[WS_CT / 4 + hh] = make_float4(t0, t1, tc + b1[hh], W2[hh]);
  }
  __syncthreads();
  if (t < 128) {
    float4* w4 = (float4*)ws;
    w4[WS_TG / 4 + t] = make_float4(mg_s[0][t], mg_s[1][t], vg[t], cg_s[t]);
    w4[WS_TP / 4 + t] = make_float4(mp_s[0][t], mp_s[1][t], vp[t], cp_s[t]);
    w4[WS_TQ / 4 + t] = make_float4(pg_s[0][t], pg_s[1][t], pc_s[t], 0.f);
  }
  {
    int j = t;
    float a0 = 0.f, a1 = 0.f, a2 = 0.f, a3 = 0.f;
    for (int k = 0; k < 128; ++k) {
      float wi = Wi[k * G4 + j];
      a0 = fmaf(Wemb[k], wi, a0);
      a1 = fmaf(Wemb[128 + k], wi, a1);
      a2 = fmaf(bemb[k], wi, a2);
      a3 = fmaf(dinit[k], wi, a3);
    }
    ws[WS_A0 + j] = a0;
    ws[WS_A1 + j] = a1;
    ws[WS_A2 + j] = a2 + bl[j];
    ws[WS_A3 + j] = a3 + bl[j];
  }
}

// Persistent: 512 blocks x 512 threads, 2 rows/block, 2 blocks/CU.
// __launch_bounds__(512, 2): min 2 waves/EU -> 256-VGPR cap so the
// register-resident weights (wv[32]x4 + wqr[32] = 160 regs) do NOT spill
// (round 9's regression was the (512,4) bound forcing a 128-reg cap ->
// scratch spill -> 4.7 GB re-fetch). 12 KB dynamic LDS at launch pads the
// block to ~57 KB so exactly 2 blocks/CU fit (3x57 > 160 KB): one block's
// waves issue through the other's barrier drains.
// 5 barriers/step: A1+F' | A2 | B | C | DE.
extern __shared__ float dynpad[];
__global__ __launch_bounds__(512, 2) void k_mega(const float* __restrict__ ip,
                                                 const float* __restrict__ Wh,
                                                 const float* __restrict__ Wqg,
                                                 const float* __restrict__ b2,
                                                 const float* __restrict__ ws,
                                                 float* __restrict__ out) {
  __shared__ __align__(16) float gpart[4][2][G4];     // 16 KB
  __shared__ __align__(16) float qpart[4][2][Hd];     // 4 KB
  __shared__ __align__(16) float up_s[4][2][64];      // glimpse partials
  __shared__ __align__(16) float up2_s[4][2][64];     // pointer partials
  __shared__ __align__(16) float q_w[2][Hd];          // query exchange (x2 scaled)
  __shared__ __align__(16) float h_s[2][Hd];
  __shared__ __align__(16) float c_s[2][Hd];
  __shared__ __align__(16) float tg_s[G4];            // {2Mg0,2Mg1,-2vg,2cg}
  __shared__ __align__(16) float tp_s[G4];            // {2Mp0,2Mp1,-2vp,0}
  __shared__ __align__(16) float tq_s[G4];            // {2Pg0,2Pg1,2pc,0}
  __shared__ __align__(16) float ct_s[G4];
  __shared__ __align__(16) float a0_s[G4], a1_s[G4], a2_s[G4], a3_s[G4];
  __shared__ float vsum_s[2][4];                      // sum(v) per 32-chunk
  __shared__ __align__(16) float ip_s[2][Npt * 2];
  __shared__ float mask_s[2][Npt];
  __shared__ float ch_s[2][Npt * 2];
  __shared__ float sel_s[2][2];

  int t = threadIdx.x, blk = blockIdx.x;
  int w = t >> 6, lane = t & 63;
  int kh = t >> 7, jt = t & 127;     // 4 k-chunks x 128 cols

  // ---- register-resident weights (160 VGPRs; fits under the 256 cap) ----
  float4 wv[32];                     // Wh[kh*32 .. +32)[jt*4 .. +4)
  #pragma unroll
  for (int j = 0; j < 32; ++j)
    wv[j] = *(const float4*)&Wh[(kh * 32 + j) * G4 + jt * 4];
  float wqr[32];                     // Wqg[kh*32 .. +32)[jt]
  #pragma unroll
  for (int j = 0; j < 32; ++j)
    wqr[j] = Wqg[(kh * 32 + j) * Hd + jt];

  // ---- stage tables (scaled) + per-block state ----
  const float4* ws4 = (const float4*)ws;
  if (t < 128) {
    float4 g4 = ws4[WS_TG / 4 + t];
    ((float4*)tg_s)[t] = make_float4(2.f * g4.x, 2.f * g4.y, -2.f * g4.z, 2.f * g4.w);
    float4 p4 = ws4[WS_TP / 4 + t];
    ((float4*)tp_s)[t] = make_float4(2.f * p4.x, 2.f * p4.y, -2.f * p4.z, 0.f);
    float4 q4 = ws4[WS_TQ / 4 + t];
    ((float4*)tq_s)[t] = make_float4(2.f * q4.x, 2.f * q4.y, 2.f * q4.z, 0.f);
    ((float4*)ct_s)[t] = ws4[WS_CT / 4 + t];
  } else if (t < 256) {
    int i = t - 128;
    ((float4*)a0_s)[i] = ((const float4*)(ws + WS_A0))[i];
    ((float4*)a1_s)[i] = ((const float4*)(ws + WS_A1))[i];
    ((float4*)a2_s)[i] = ((const float4*)(ws + WS_A2))[i];
    ((float4*)a3_s)[i] = ((const float4*)(ws + WS_A3))[i];
  }
  if (t < 100) {
    ((float2*)ip_s)[t] = ((const float2*)ip)[blk * 100 + t];
    ((float*)mask_s)[t] = 0.f;
  }
  if (t < 256) {
    int r = t >> 7, hh = t & 127;
    h_s[r][hh] = 0.f;
    c_s[r][hh] = 0.f;
  }
  if (t < 8) {
    int c = t & 3, which = t >> 2;
    float s = 0.f;
    for (int hp = 0; hp < 32; ++hp)
      s += ws[(which ? WS_TP : WS_TG) + (c * 32 + hp) * 4 + 2];
    vsum_s[which][c] = s;
  }
  if (t < 4) ((float*)sel_s)[t] = 0.f;
  __syncthreads();

  int cr = w & 1, cc = w >> 1;       // C/E wave = (row, 32-h chunk)
  float2 pn = make_float2(0.f, 0.f);
  if (lane < Npt) pn = ((float2*)ip_s)[cr * Npt + lane];

  for (int st = 0; st < Tt; ++st) {
    // ---- phase1: A1 (h@Wh partials) + F(st-1) on waves 6,7 ----
    {
      int k0 = kh * 32;
      #pragma unroll
      for (int r = 0; r < 2; ++r) {
        float hv[32];
        #pragma unroll
        for (int q8 = 0; q8 < 8; ++q8)
          *(float4*)&hv[q8 * 4] = *(const float4*)&h_s[r][k0 + q8 * 4];
        float a0 = 0.f, a1 = 0.f, a2 = 0.f, a3 = 0.f;
        #pragma unroll
        for (int kk = 0; kk < 32; ++kk) {
          float4 wj = wv[kk];
          a0 = fmaf(hv[kk], wj.x, a0);
          a1 = fmaf(hv[kk], wj.y, a1);
          a2 = fmaf(hv[kk], wj.z, a2);
          a3 = fmaf(hv[kk], wj.w, a3);
        }
        *(float4*)&gpart[kh][r][jt * 4] = make_float4(a0, a1, a2, a3);
      }
    }
    if (w >= 6 && st > 0) {            // F(st-1): finalize previous step
      int r = w - 6, stp = st - 1, b = blk * 2 + r;
      float u = up2_s[0][r][lane] + up2_s[1][r][lane]
              + up2_s[2][r][lane] + up2_s[3][r][lane];
      float x = 0.f, e = 0.f;
      if (lane < Npt) {
        x = CTANH * ftanh(u) - NEGC * mask_s[r][lane];
        e = __expf(x);
      }
      float ssum = dpp_sum_bcast(e);
      float ls = __logf(ssum);
      float prob = e / ssum;
      if (lane < Npt) {
        out[OFF_LP + ((size_t)b * Tt + stp) * Npt + lane] = x - ls;
        out[OFF_P + ((size_t)b * Tt + stp) * Npt + lane] = prob;
      }
      float mx = dpp_max_bcast(prob);
      unsigned long long bal = __ballot((prob == mx) && (lane < Npt));
      int a = __ffsll(bal) - 1;        // first-index tie-break
      float p0a = ip_s[r][2 * a];
      float p1a = ip_s[r][2 * a + 1];
      if (lane == 0) {
        out[OFF_A + (size_t)b * Tt + stp] = (float)a;
        out[OFF_C + ((size_t)b * Tt + stp) * 2 + 0] = p0a;
        out[OFF_C + ((size_t)b * Tt + stp) * 2 + 1] = p1a;
        ((float2*)ch_s)[r * Npt + stp] = make_float2(p0a, p1a);
        mask_s[r][a] = 1.0f;
        sel_s[r][0] = p0a;
        sel_s[r][1] = p1a;
      }
    }
    __syncthreads();
    // ---- A2: combine + rank-2 x-part + LSTM cell ----
    if (t < 256) {
      int r = t >> 7, hh = t & 127;
      float p0 = sel_s[r][0], p1 = sel_s[r][1];
      float g[4];
      #pragma unroll
      for (int gi = 0; gi < 4; ++gi) {
        int j = gi * 128 + hh;
        float x = (st == 0) ? a3_s[j]
                            : fmaf(p0, a0_s[j], fmaf(p1, a1_s[j], a2_s[j]));
        x += gpart[0][r][j] + gpart[1][r][j] + gpart[2][r][j] + gpart[3][r][j];
        g[gi] = x;
      }
      float c2 = fsig(g[1]) * c_s[r][hh] + fsig(g[0]) * ftanh(g[2]);
      float h2 = fsig(g[3]) * ftanh(c2);
      c_s[r][hh] = c2;
      h_s[r][hh] = h2;
    }
    __syncthreads();
    // ---- B: qpart = h2 @ Wqg (k-split 4-way, register weights) ----
    {
      int k0 = kh * 32;
      #pragma unroll
      for (int r = 0; r < 2; ++r) {
        float hv[32];
        #pragma unroll
        for (int q8 = 0; q8 < 8; ++q8)
          *(float4*)&hv[q8 * 4] = *(const float4*)&h_s[r][k0 + q8 * 4];
        float a = 0.f;
        #pragma unroll
        for (int kk = 0; kk < 32; ++kk) a = fmaf(hv[kk], wqr[kk], a);
        qpart[kh][r][jt] = a;
      }
    }
    __syncthreads();
    // ---- C: glimpse scores; wave=(row,32-h chunk), n per lane ----
    {
      if (lane < 32) {                 // in-wave q combine (x2 scaled)
        int h = cc * 32 + lane;
        float qs = ((float4*)tg_s)[h].w   // = 2*cg
                 + 2.f * (qpart[0][cr][h] + qpart[1][cr][h]
                        + qpart[2][cr][h] + qpart[3][cr][h]);
        q_w[cr][h] = qs;
      }
      float ac = vsum_s[0][cc];
      #pragma unroll
      for (int hp4 = 0; hp4 < 8; ++hp4) {
        float4 qv = ((float4*)&q_w[cr][cc * 32])[hp4];
        float qa[4] = {qv.x, qv.y, qv.z, qv.w};
        #pragma unroll
        for (int k = 0; k < 4; ++k) {
          float4 tg4 = ((float4*)tg_s)[cc * 32 + hp4 * 4 + k];
          float a = fmaf(pn.x, tg4.x, fmaf(pn.y, tg4.y, qa[k]));
          float rc = __builtin_amdgcn_rcpf(__expf(a) + 1.0f);
          ac = fmaf(tg4.z, rc, ac);    // tg4.z = -2*vg
        }
      }
      up_s[cc][cr][lane] = ac;
    }
    __syncthreads();
    // ---- DE: glimpse softmax (dup per wave) + pointer scores ----
    {
      float u = up_s[0][cr][lane] + up_s[1][cr][lane]
              + up_s[2][cr][lane] + up_s[3][cr][lane];
      float e = 0.f;
      if (lane < Npt) e = __expf(u - NEGC * mask_s[cr][lane]);
      float ssum = dpp_sum_bcast(e);
      float p = e / ssum;
      float s0 = dpp_sum_bcast(p * pn.x);
      float s1 = dpp_sum_bcast(p * pn.y);
      if (lane < 32) {
        int h = cc * 32 + lane;
        float4 tq4 = ((float4*)tq_s)[h];   // {2Pg0,2Pg1,2pc}
        q_w[cr][h] = fmaf(s0, tq4.x, fmaf(s1, tq4.y, tq4.z));
      }
      float ac = vsum_s[1][cc];
      #pragma unroll
      for (int hp4 = 0; hp4 < 8; ++hp4) {
        float4 qv = ((float4*)&q_w[cr][cc * 32])[hp4];
        float qa[4] = {qv.x, qv.y, qv.z, qv.w};
        #pragma unroll
        for (int k = 0; k < 4; ++k) {
          float4 tp4 = ((float4*)tp_s)[cc * 32 + hp4 * 4 + k];
          float a = fmaf(pn.x, tp4.x, fmaf(pn.y, tp4.y, qa[k]));
          float rc = __builtin_amdgcn_rcpf(__expf(a) + 1.0f);
          ac = fmaf(tp4.z, rc, ac);    // tp4.z = -2*vp
        }
      }
      up2_s[cc][cr][lane] = ac;
    }
    __syncthreads();
  }

  // ---- final F (st = Tt-1) ----
  if (w >= 6) {
    int r = w - 6, stp = Tt - 1, b = blk * 2 + r;
    float u = up2_s[0][r][lane] + up2_s[1][r][lane]
            + up2_s[2][r][lane] + up2_s[3][r][lane];
    float x = 0.f, e = 0.f;
    if (lane < Npt) {
      x = CTANH * ftanh(u) - NEGC * mask_s[r][lane];
      e = __expf(x);
    }
    float ssum = dpp_sum_bcast(e);
    float ls = __logf(ssum);
    float prob = e / ssum;
    if (lane < Npt) {
      out[OFF_LP + ((size_t)b * Tt + stp) * Npt + lane] = x - ls;
      out[OFF_P + ((size_t)b * Tt + stp) * Npt + lane] = prob;
    }
    float mx = dpp_max_bcast(prob);
    unsigned long long bal = __ballot((prob == mx) && (lane < Npt));
    int a = __ffsll(bal) - 1;
    float p0a = ip_s[r][2 * a];
    float p1a = ip_s[r][2 * a + 1];
    if (lane == 0) {
      out[OFF_A + (size_t)b * Tt + stp] = (float)a;
      out[OFF_C + ((size_t)b * Tt + stp) * 2 + 0] = p0a;
      out[OFF_C + ((size_t)b * Tt + stp) * 2 + 1] = p1a;
      ((float2*)ch_s)[r * Npt + stp] = make_float2(p0a, p1a);
      sel_s[r][0] = p0a;
      sel_s[r][1] = p1a;
    }
  }
  __syncthreads();

  // ---- epilogue: collapsed critic + tour length ----
  if (w < 2) {
    int r = w, b = blk * 2 + r;
    float p0 = sel_s[r][0], p1 = sel_s[r][1];
    float4 ct0 = ((float4*)ct_s)[lane];
    float4 ct1 = ((float4*)ct_s)[64 + lane];
    float t1a = fmaxf(fmaf(p0, ct0.x, fmaf(p1, ct0.y, ct0.z)), 0.f);
    float t1b = fmaxf(fmaf(p0, ct1.x, fmaf(p1, ct1.y, ct1.z)), 0.f);
    float sv = xsum(t1a * ct0.w + t1b * ct1.w);
    if (lane == 0) out[OFF_V + b] = sv + b2[0];
    float rr = 0.f;
    if (lane < Npt) {
      float2 c0 = ((float2*)ch_s)[r * Npt + lane];
      float2 c1 = ((float2*)ch_s)[r * Npt + ((lane == Npt - 1) ? 0 : lane + 1)];
      float dx = c1.x - c0.x, dy = c1.y - c0.y;
      rr = sqrtf(dx * dx + dy * dy + 1e-10f);
    }
    rr = xsum(rr);
    if (lane == 0) out[OFF_R + b] = rr;
  }
}

extern "C" void kernel_launch(void* const* d_in, const int* in_sizes, int n_in,
                              void* d_out, int out_size, void* d_ws, size_t ws_size,
                              hipStream_t stream) {
  (void)in_sizes; (void)n_in; (void)out_size; (void)ws_size;
  const float* ip    = (const float*)d_in[0];
  const float* Wemb  = (const float*)d_in[1];
  const float* bemb  = (const float*)d_in[2];
  const float* dinit = (const float*)d_in[3];
  const float* Wi    = (const float*)d_in[4];
  const float* Wh    = (const float*)d_in[5];
  const float* bl    = (const float*)d_in[6];
  const float* Wqg   = (const float*)d_in[7];
  const float* Wrg   = (const float*)d_in[8];
  const float* vg    = (const float*)d_in[9];
  const float* Wqp   = (const float*)d_in[10];
  const float* Wrp   = (const float*)d_in[11];
  const float* vp    = (const float*)d_in[12];
  // d_in[13..16], d_in[18] dead: critic N=1 softmax == 1 => hy = e_c
  const float* Wrc   = (const float*)d_in[17];
  const float* W1    = (const float*)d_in[19];
  const float* b1    = (const float*)d_in[20];
  const float* W2    = (const float*)d_in[21];
  const float* b2    = (const float*)d_in[22];
  float* out = (float*)d_out;
  float* ws  = (float*)d_ws;

  k_pre<<<1, 512, 0, stream>>>(Wemb, bemb, dinit, Wi, bl, Wqp, Wrg, Wrp,
                               vg, vp, Wrc, W1, b1, W2, ws);
  // 12 KB dynamic LDS: pads block to ~57 KB so exactly 2 blocks/CU fit.
  k_mega<<<512, 512, 12288, stream>>>(ip, Wh, Wqg, b2, ws, out);
}

// Round 13
// 620.011 us; speedup vs baseline: 1.0203x; 1.0203x over previous
//
#include <hip/hip_runtime.h>
#include <math.h>

#define Bsz 1024
#define Npt 50
#define Hd 128
#define G4 512
#define Tt 50
#define NEGC 1000000000.0f
#define CTANH 10.0f

#define OFF_R 0
#define OFF_V 1024
#define OFF_LP 2048
#define OFF_A 2562048
#define OFF_C 2613248
#define OFF_P 2715648

// ws float offsets (all tables; no bulk state)
#define WS_TG 0        // 128 float4 {Mg0, Mg1, vg, cg}
#define WS_TP 512      // 128 float4 {Mp0, Mp1, vp, cp}
#define WS_TQ 1024     // 128 float4 {Pg0, Pg1, cg@Wqp+cp, 0}
#define WS_A0 1536     // 512: We0@Wi
#define WS_A1 2048     // 512: We1@Wi
#define WS_A2 2560     // 512: bemb@Wi + bl
#define WS_A3 3072     // 512: dec_init@Wi + bl   (step 0)
#define WS_CT 3584     // 128 float4 {T0, T1, Tc(+b1), W2}

__device__ __forceinline__ float fsig(float x) {
  return __builtin_amdgcn_rcpf(1.0f + __expf(-x));
}

__device__ __forceinline__ float ftanh(float x) {
  float e = __expf(2.0f * x);
  return 1.0f - 2.0f * __builtin_amdgcn_rcpf(e + 1.0f);
}

__device__ __forceinline__ float dpp_sum_bcast(float x) {
  int v;
  v = __builtin_amdgcn_update_dpp(0, __float_as_int(x), 0x111, 0xf, 0xf, true);
  x += __int_as_float(v);
  v = __builtin_amdgcn_update_dpp(0, __float_as_int(x), 0x112, 0xf, 0xf, true);
  x += __int_as_float(v);
  v = __builtin_amdgcn_update_dpp(0, __float_as_int(x), 0x114, 0xf, 0xf, true);
  x += __int_as_float(v);
  v = __builtin_amdgcn_update_dpp(0, __float_as_int(x), 0x118, 0xf, 0xf, true);
  x += __int_as_float(v);
  v = __builtin_amdgcn_update_dpp(0, __float_as_int(x), 0x142, 0xf, 0xf, true);
  x += __int_as_float(v);
  v = __builtin_amdgcn_update_dpp(0, __float_as_int(x), 0x143, 0xf, 0xf, true);
  x += __int_as_float(v);
  return __int_as_float(__builtin_amdgcn_readlane(__float_as_int(x), 63));
}

// wave64 max via DPP; REQUIRES x >= 0
__device__ __forceinline__ float dpp_max_bcast(float x) {
  int v;
  v = __builtin_amdgcn_update_dpp(0, __float_as_int(x), 0x111, 0xf, 0xf, true);
  x = fmaxf(x, __int_as_float(v));
  v = __builtin_amdgcn_update_dpp(0, __float_as_int(x), 0x112, 0xf, 0xf, true);
  x = fmaxf(x, __int_as_float(v));
  v = __builtin_amdgcn_update_dpp(0, __float_as_int(x), 0x114, 0xf, 0xf, true);
  x = fmaxf(x, __int_as_float(v));
  v = __builtin_amdgcn_update_dpp(0, __float_as_int(x), 0x118, 0xf, 0xf, true);
  x = fmaxf(x, __int_as_float(v));
  v = __builtin_amdgcn_update_dpp(0, __float_as_int(x), 0x142, 0xf, 0xf, true);
  x = fmaxf(x, __int_as_float(v));
  v = __builtin_amdgcn_update_dpp(0, __float_as_int(x), 0x143, 0xf, 0xf, true);
  x = fmaxf(x, __int_as_float(v));
  return __int_as_float(__builtin_amdgcn_readlane(__float_as_int(x), 63));
}

__device__ __forceinline__ float xsum(float x) {
  #pragma unroll
  for (int off = 32; off >= 1; off >>= 1) x += __shfl_xor(x, off, 64);
  return x;
}

// One block, 512 threads: all rank-2 tables + collapsed critic tables.
__global__ __launch_bounds__(512) void k_pre(const float* __restrict__ Wemb,
                                             const float* __restrict__ bemb,
                                             const float* __restrict__ dinit,
                                             const float* __restrict__ Wi,
                                             const float* __restrict__ bl,
                                             const float* __restrict__ Wqp,
                                             const float* __restrict__ Wrg,
                                             const float* __restrict__ Wrp,
                                             const float* __restrict__ vg,
                                             const float* __restrict__ vp,
                                             const float* __restrict__ Wrc,
                                             const float* __restrict__ W1,
                                             const float* __restrict__ b1,
                                             const float* __restrict__ W2,
                                             float* __restrict__ ws) {
  __shared__ float mg_s[2][128], mp_s[2][128], cg_s[128], cp_s[128];
  __shared__ float pg_s[2][128], pc_s[128];
  __shared__ float r0_s[128], r1_s[128], rc_s[128];
  int t = threadIdx.x;
  if (t < 256) {
    int j = t >> 7, hh = t & 127;
    float ag = 0.f, ap = 0.f;
    for (int k = 0; k < 128; ++k) {
      float we = Wemb[j * 128 + k];
      ag = fmaf(we, Wrg[k * 128 + hh], ag);
      ap = fmaf(we, Wrp[k * 128 + hh], ap);
    }
    mg_s[j][hh] = ag; mp_s[j][hh] = ap;
  } else if (t < 384) {
    int hh = t & 127;
    float cgv = 0.f, cpv = 0.f;
    for (int k = 0; k < 128; ++k) {
      float be = bemb[k];
      cgv = fmaf(be, Wrg[k * 128 + hh], cgv);
      cpv = fmaf(be, Wrp[k * 128 + hh], cpv);
    }
    cg_s[hh] = cgv; cp_s[hh] = cpv;
  } else {
    int hh = t & 127;
    float a0 = 0.f, a1 = 0.f, ac = 0.f;
    for (int k = 0; k < 128; ++k) {
      float wr = Wrc[k * 128 + hh];
      a0 = fmaf(Wemb[k], wr, a0);
      a1 = fmaf(Wemb[128 + k], wr, a1);
      ac = fmaf(bemb[k], wr, ac);
    }
    r0_s[hh] = a0; r1_s[hh] = a1; rc_s[hh] = ac;
  }
  __syncthreads();
  if (t < 256) {
    int j = t >> 7, hh = t & 127;
    float pg = 0.f;
    for (int k = 0; k < 128; ++k) pg = fmaf(mg_s[j][k], Wqp[k * 128 + hh], pg);
    pg_s[j][hh] = pg;
  } else if (t < 384) {
    int hh = t & 127;
    float pcv = 0.f;
    for (int k = 0; k < 128; ++k) pcv = fmaf(cg_s[k], Wqp[k * 128 + hh], pcv);
    pc_s[hh] = pcv + cp_s[hh];
  } else {
    int hh = t & 127;
    float t0 = 0.f, t1 = 0.f, tc = 0.f;
    for (int k = 0; k < 128; ++k) {
      float w1 = W1[k * 128 + hh];
      t0 = fmaf(r0_s[k], w1, t0);
      t1 = fmaf(r1_s[k], w1, t1);
      tc = fmaf(rc_s[k], w1, tc);
    }
    float4* w4 = (float4*)ws;
    w4[WS_CT / 4 + hh] = make_float4(t0, t1, tc + b1[hh], W2[hh]);
  }
  __syncthreads();
  if (t < 128) {
    float4* w4 = (float4*)ws;
    w4[WS_TG / 4 + t] = make_float4(mg_s[0][t], mg_s[1][t], vg[t], cg_s[t]);
    w4[WS_TP / 4 + t] = make_float4(mp_s[0][t], mp_s[1][t], vp[t], cp_s[t]);
    w4[WS_TQ / 4 + t] = make_float4(pg_s[0][t], pg_s[1][t], pc_s[t], 0.f);
  }
  {
    int j = t;
    float a0 = 0.f, a1 = 0.f, a2 = 0.f, a3 = 0.f;
    for (int k = 0; k < 128; ++k) {
      float wi = Wi[k * G4 + j];
      a0 = fmaf(Wemb[k], wi, a0);
      a1 = fmaf(Wemb[128 + k], wi, a1);
      a2 = fmaf(bemb[k], wi, a2);
      a3 = fmaf(dinit[k], wi, a3);
    }
    ws[WS_A0 + j] = a0;
    ws[WS_A1 + j] = a1;
    ws[WS_A2 + j] = a2 + bl[j];
    ws[WS_A3 + j] = a3 + bl[j];
  }
}

// Persistent: 256 blocks x 1024 threads (16 waves, 4/SIMD), 4 rows/block.
// Wh(64f)+Wqg(16f) register-resident (80 regs, no spill). 5 barriers/step:
//   P1: A1(s) + F(s-1) on waves 12-15   (A1 doesn't depend on F)
//   P2: A2  P3: B  P4: C  P5: DE
// Scores: rcp-form with x2 pre-scaled tables; DPP reductions; no max-subtract
// (u bounded by sum|v|, logits by +/-10); conflict-free LDS layouts.
// DE softmax: three INDEPENDENT dpp sums (Se, Se*x, Se*y) + one rcp --
// interleavable cascades, no full-precision divide. prob = e*rcp(ssum) is
// monotone in e -> argmax/trajectory identical.
__global__ __launch_bounds__(1024, 4) void k_mega(const float* __restrict__ ip,
                                                  const float* __restrict__ Wh,
                                                  const float* __restrict__ Wqg,
                                                  const float* __restrict__ b2,
                                                  const float* __restrict__ ws,
                                                  float* __restrict__ out) {
  __shared__ __align__(16) float gpart[8][4][G4];     // 64 KB
  __shared__ __align__(16) float qpart[8][4][Hd];     // 16 KB
  __shared__ __align__(16) float up_s[4][4][64];      // 4 KB glimpse partials
  __shared__ __align__(16) float up2_s[4][4][64];     // 4 KB pointer partials
  __shared__ __align__(16) float qc_s[4][Hd];         // 2 KB query exchange
  __shared__ __align__(16) float h_s[4][Hd];
  __shared__ __align__(16) float c_s[4][Hd];
  __shared__ __align__(16) float tg_s[G4];            // {2Mg0,2Mg1,-2vg,2cg}
  __shared__ __align__(16) float tp_s[G4];            // {2Mp0,2Mp1,-2vp,0}
  __shared__ __align__(16) float tq_s[G4];            // {2Pg0,2Pg1,2pc,0}
  __shared__ __align__(16) float ct_s[G4];
  __shared__ __align__(16) float a0_s[G4], a1_s[G4], a2_s[G4], a3_s[G4];
  __shared__ float vsum_s[2][4];                      // sum(v) per 32-h chunk
  __shared__ __align__(16) float ip_s[4][Npt * 2];
  __shared__ float mask_s[4][Npt];
  __shared__ float ch_s[4][Npt * 2];
  __shared__ float sel_s[4][2];

  int t = threadIdx.x, blk = blockIdx.x;
  int w = t >> 6, lane = t & 63;
  int kh = t >> 7, jt = t & 127;     // 8 k-chunks x 128 cols

  // ---- register-resident weights (80 VGPRs) ----
  float4 wv[16];                     // Wh[kh*16 .. +16)[jt*4 .. +4)
  #pragma unroll
  for (int j = 0; j < 16; ++j)
    wv[j] = *(const float4*)&Wh[(kh * 16 + j) * G4 + jt * 4];
  float wqr[16];                     // Wqg[kh*16 .. +16)[jt]
  #pragma unroll
  for (int j = 0; j < 16; ++j)
    wqr[j] = Wqg[(kh * 16 + j) * Hd + jt];

  // ---- stage tables (x2 pre-scale) + per-block state ----
  const float4* ws4 = (const float4*)ws;
  if (t < 128) {
    float4 g4 = ws4[WS_TG / 4 + t];
    ((float4*)tg_s)[t] = make_float4(2.f * g4.x, 2.f * g4.y, -2.f * g4.z, 2.f * g4.w);
    float4 p4 = ws4[WS_TP / 4 + t];
    ((float4*)tp_s)[t] = make_float4(2.f * p4.x, 2.f * p4.y, -2.f * p4.z, 0.f);
    float4 q4 = ws4[WS_TQ / 4 + t];
    ((float4*)tq_s)[t] = make_float4(2.f * q4.x, 2.f * q4.y, 2.f * q4.z, 0.f);
    ((float4*)ct_s)[t] = ws4[WS_CT / 4 + t];
  } else if (t < 256) {
    int i = t - 128;
    ((float4*)a0_s)[i] = ((const float4*)(ws + WS_A0))[i];
    ((float4*)a1_s)[i] = ((const float4*)(ws + WS_A1))[i];
    ((float4*)a2_s)[i] = ((const float4*)(ws + WS_A2))[i];
    ((float4*)a3_s)[i] = ((const float4*)(ws + WS_A3))[i];
  }
  if (t < 200) {
    ((float2*)ip_s)[t] = ((const float2*)ip)[blk * 200 + t];
    ((float*)mask_s)[t] = 0.f;
  }
  if (t < 512) {
    int r = t >> 7, hh = t & 127;
    h_s[r][hh] = 0.f;
    c_s[r][hh] = 0.f;
  }
  if (t < 8) {          // vsum per 32-h chunk (raw v from ws tables)
    int which = t >> 2, c = t & 3;
    float s = 0.f;
    for (int hp = 0; hp < 32; ++hp)
      s += ws[(which ? WS_TP : WS_TG) + (c * 32 + hp) * 4 + 2];
    vsum_s[which][c] = s;
  }
  if (t < 8) ((float*)sel_s)[t] = 0.f;
  __syncthreads();

  // C/DE/F wave roles: row = w&3, hc = w>>2 in [0,4): 32-h chunk.
  int cr = w & 3, hc = w >> 2;
  float2 pn = make_float2(0.f, 0.f);
  if (lane < Npt) pn = ((float2*)ip_s)[cr * Npt + lane];

  for (int s = 0; s < Tt; ++s) {
    // ---- P1: A1 (all waves) + F(s-1) on waves 12-15 ----
    {
      int k0 = kh * 16;
      #pragma unroll
      for (int r = 0; r < 4; ++r) {
        float hv[16];
        #pragma unroll
        for (int q4i = 0; q4i < 4; ++q4i)
          *(float4*)&hv[q4i * 4] = *(const float4*)&h_s[r][k0 + q4i * 4];
        float a0 = 0.f, a1 = 0.f, a2 = 0.f, a3 = 0.f;
        #pragma unroll
        for (int kk = 0; kk < 16; ++kk) {
          float4 wj = wv[kk];
          a0 = fmaf(hv[kk], wj.x, a0);
          a1 = fmaf(hv[kk], wj.y, a1);
          a2 = fmaf(hv[kk], wj.z, a2);
          a3 = fmaf(hv[kk], wj.w, a3);
        }
        *(float4*)&gpart[kh][r][jt * 4] = make_float4(a0, a1, a2, a3);
      }
      if (w >= 12 && s > 0) {          // F(s-1)
        int row = cr, stp = s - 1, b = blk * 4 + row;
        float u = up2_s[0][row][lane] + up2_s[1][row][lane]
                + up2_s[2][row][lane] + up2_s[3][row][lane];
        float x = 0.f, e = 0.f;
        if (lane < Npt) {
          x = CTANH * ftanh(u) - NEGC * mask_s[row][lane];
          e = __expf(x);
        }
        float ssum = dpp_sum_bcast(e);
        float ls = __logf(ssum);
        float prob = e * __builtin_amdgcn_rcpf(ssum);
        if (lane < Npt) {
          out[OFF_LP + ((size_t)b * Tt + stp) * Npt + lane] = x - ls;
          out[OFF_P + ((size_t)b * Tt + stp) * Npt + lane] = prob;
        }
        float mx = dpp_max_bcast(prob);
        unsigned long long bal = __ballot((prob == mx) && (lane < Npt));
        int a = __ffsll(bal) - 1;      // first-index tie-break
        float p0a = ip_s[row][2 * a];
        float p1a = ip_s[row][2 * a + 1];
        if (lane == 0) {
          out[OFF_A + (size_t)b * Tt + stp] = (float)a;
          out[OFF_C + ((size_t)b * Tt + stp) * 2 + 0] = p0a;
          out[OFF_C + ((size_t)b * Tt + stp) * 2 + 1] = p1a;
          ((float2*)ch_s)[row * Npt + stp] = make_float2(p0a, p1a);
          mask_s[row][a] = 1.0f;
          sel_s[row][0] = p0a;
          sel_s[row][1] = p1a;
        }
      }
    }
    __syncthreads();
    // ---- P2: A2 combine + rank-2 x-part + LSTM cell ----
    if (t < 512) {
      int r = t >> 7, hh = t & 127;
      float p0 = sel_s[r][0], p1 = sel_s[r][1];
      float g[4];
      #pragma unroll
      for (int gi = 0; gi < 4; ++gi) {
        int j = gi * 128 + hh;
        float x = (s == 0) ? a3_s[j]
                           : fmaf(p0, a0_s[j], fmaf(p1, a1_s[j], a2_s[j]));
        #pragma unroll
        for (int k8 = 0; k8 < 8; ++k8) x += gpart[k8][r][j];
        g[gi] = x;
      }
      float c2 = fsig(g[1]) * c_s[r][hh] + fsig(g[0]) * ftanh(g[2]);
      float h2 = fsig(g[3]) * ftanh(c2);
      c_s[r][hh] = c2;
      h_s[r][hh] = h2;
    }
    __syncthreads();
    // ---- P3: B qpart = h2 @ Wqg (k-split 8-way, register weights) ----
    {
      int k0 = kh * 16;
      #pragma unroll
      for (int r = 0; r < 4; ++r) {
        float hv[16];
        #pragma unroll
        for (int q4i = 0; q4i < 4; ++q4i)
          *(float4*)&hv[q4i * 4] = *(const float4*)&h_s[r][k0 + q4i * 4];
        float a = 0.f;
        #pragma unroll
        for (int kk = 0; kk < 16; ++kk) a = fmaf(hv[kk], wqr[kk], a);
        qpart[kh][r][jt] = a;
      }
    }
    __syncthreads();
    // ---- P4: C glimpse scores; wave=(row,32-h chunk), n per lane ----
    {
      if (lane < 32) {                 // in-wave q combine (x2 scaled)
        int h = hc * 32 + lane;
        float qs = ((float4*)tg_s)[h].w
                 + 2.f * (qpart[0][cr][h] + qpart[1][cr][h] + qpart[2][cr][h]
                        + qpart[3][cr][h] + qpart[4][cr][h] + qpart[5][cr][h]
                        + qpart[6][cr][h] + qpart[7][cr][h]);
        qc_s[cr][h] = qs;
      }
      float ac = vsum_s[0][hc];
      #pragma unroll 8
      for (int hp = 0; hp < 32; ++hp) {
        int h = hc * 32 + hp;
        float4 tg4 = ((float4*)tg_s)[h];
        float a = fmaf(pn.x, tg4.x, fmaf(pn.y, tg4.y, qc_s[cr][h]));
        ac = fmaf(tg4.z, __builtin_amdgcn_rcpf(__expf(a) + 1.0f), ac);
      }
      up_s[hc][cr][lane] = ac;
    }
    __syncthreads();
    // ---- P5: DE glimpse softmax (dup per wave) + pointer scores ----
    {
      float u = up_s[0][cr][lane] + up_s[1][cr][lane]
              + up_s[2][cr][lane] + up_s[3][cr][lane];
      float e = 0.f;
      if (lane < Npt) e = __expf(u - NEGC * mask_s[cr][lane]);
      float ssum = dpp_sum_bcast(e);
      float sx = dpp_sum_bcast(e * pn.x);
      float sy = dpp_sum_bcast(e * pn.y);
      float inv = __builtin_amdgcn_rcpf(ssum);
      float s0 = sx * inv;
      float s1 = sy * inv;
      if (lane < 32) {
        int h = hc * 32 + lane;
        float4 tq4 = ((float4*)tq_s)[h];
        qc_s[cr][h] = fmaf(s0, tq4.x, fmaf(s1, tq4.y, tq4.z));
      }
      float ac = vsum_s[1][hc];
      #pragma unroll 8
      for (int hp = 0; hp < 32; ++hp) {
        int h = hc * 32 + hp;
        float4 tp4 = ((float4*)tp_s)[h];
        float a = fmaf(pn.x, tp4.x, fmaf(pn.y, tp4.y, qc_s[cr][h]));
        ac = fmaf(tp4.z, __builtin_amdgcn_rcpf(__expf(a) + 1.0f), ac);
      }
      up2_s[hc][cr][lane] = ac;
    }
    __syncthreads();
  }

  // ---- drain: F(Tt-1) on waves 12-15 ----
  if (w >= 12) {
    int row = cr, stp = Tt - 1, b = blk * 4 + row;
    float u = up2_s[0][row][lane] + up2_s[1][row][lane]
            + up2_s[2][row][lane] + up2_s[3][row][lane];
    float x = 0.f, e = 0.f;
    if (lane < Npt) {
      x = CTANH * ftanh(u) - NEGC * mask_s[row][lane];
      e = __expf(x);
    }
    float ssum = dpp_sum_bcast(e);
    float ls = __logf(ssum);
    float prob = e * __builtin_amdgcn_rcpf(ssum);
    if (lane < Npt) {
      out[OFF_LP + ((size_t)b * Tt + stp) * Npt + lane] = x - ls;
      out[OFF_P + ((size_t)b * Tt + stp) * Npt + lane] = prob;
    }
    float mx = dpp_max_bcast(prob);
    unsigned long long bal = __ballot((prob == mx) && (lane < Npt));
    int a = __ffsll(bal) - 1;
    float p0a = ip_s[row][2 * a];
    float p1a = ip_s[row][2 * a + 1];
    if (lane == 0) {
      out[OFF_A + (size_t)b * Tt + stp] = (float)a;
      out[OFF_C + ((size_t)b * Tt + stp) * 2 + 0] = p0a;
      out[OFF_C + ((size_t)b * Tt + stp) * 2 + 1] = p1a;
      ((float2*)ch_s)[row * Npt + stp] = make_float2(p0a, p1a);
      sel_s[row][0] = p0a;
      sel_s[row][1] = p1a;
    }
  }
  __syncthreads();

  // ---- epilogue: collapsed critic + tour length ----
  if (w < 4) {
    int r = w, b = blk * 4 + r;
    float p0 = sel_s[r][0], p1 = sel_s[r][1];
    float4 ct0 = ((float4*)ct_s)[lane];
    float4 ct1 = ((float4*)ct_s)[64 + lane];
    float t1a = fmaxf(fmaf(p0, ct0.x, fmaf(p1, ct0.y, ct0.z)), 0.f);
    float t1b = fmaxf(fmaf(p0, ct1.x, fmaf(p1, ct1.y, ct1.z)), 0.f);
    float sv = xsum(t1a * ct0.w + t1b * ct1.w);
    if (lane == 0) out[OFF_V + b] = sv + b2[0];
    float rr = 0.f;
    if (lane < Npt) {
      float2 c0 = ((float2*)ch_s)[r * Npt + lane];
      float2 c1 = ((float2*)ch_s)[r * Npt + ((lane == Npt - 1) ? 0 : lane + 1)];
      float dx = c1.x - c0.x, dy = c1.y - c0.y;
      rr = sqrtf(dx * dx + dy * dy + 1e-10f);
    }
    rr = xsum(rr);
    if (lane == 0) out[OFF_R + b] = rr;
  }
}

extern "C" void kernel_launch(void* const* d_in, const int* in_sizes, int n_in,
                              void* d_out, int out_size, void* d_ws, size_t ws_size,
                              hipStream_t stream) {
  (void)in_sizes; (void)n_in; (void)out_size; (void)ws_size;
  const float* ip    = (const float*)d_in[0];
  const float* Wemb  = (const float*)d_in[1];
  const float* bemb  = (const float*)d_in[2];
  const float* dinit = (const float*)d_in[3];
  const float* Wi    = (const float*)d_in[4];
  const float* Wh    = (const float*)d_in[5];
  const float* bl    = (const float*)d_in[6];
  const float* Wqg   = (const float*)d_in[7];
  const float* Wrg   = (const float*)d_in[8];
  const float* vg    = (const float*)d_in[9];
  const float* Wqp   = (const float*)d_in[10];
  const float* Wrp   = (const float*)d_in[11];
  const float* vp    = (const float*)d_in[12];
  // d_in[13..16], d_in[18] dead: critic N=1 softmax == 1 => hy = e_c
  const float* Wrc   = (const float*)d_in[17];
  const float* W1    = (const float*)d_in[19];
  const float* b1    = (const float*)d_in[20];
  const float* W2    = (const float*)d_in[21];
  const float* b2    = (const float*)d_in[22];
  float* out = (float*)d_out;
  float* ws  = (float*)d_ws;

  k_pre<<<1, 512, 0, stream>>>(Wemb, bemb, dinit, Wi, bl, Wqp, Wrg, Wrp,
                               vg, vp, Wrc, W1, b1, W2, ws);
  k_mega<<<256, 1024, 0, stream>>>(ip, Wh, Wqg, b2, ws, out);
}